// Round 1
// baseline (3865.364 us; speedup 1.0000x reference)
//
#include <hip/hip_runtime.h>
#include <math.h>

#define BS 4
#define NCH 20
#define IMH 480
#define IMW 640
#define MSZ 480
#define MPX (MSZ*MSZ)            /* 230400 */
#define VR 100

static constexpr size_t SEG = (size_t)BS*NCH*MPX;              // 18,432,000 floats per map output
static constexpr int    VOXCOL = 400;                          // ch0: 48 z  +  16 sem ch * 22 z
static constexpr size_t VOX_FLOATS = (size_t)BS*VR*VR*VOXCOL;  // 16,000,000
static constexpr size_t R_FLOATS   = (size_t)BS*19*MPX;        // 17,510,400

// workspace layout (float offsets)
static constexpr size_t OFF_AV  = 0;            // BS*18*100*100 = 720000
static constexpr size_t OFF_AVS = 720000;       // BS*100*100    = 40000
static constexpr size_t OFF_TS0 = 760000;       // BS*MPX        = 921600
static constexpr size_t OFF_PAR = 1681600;      // 64 floats

__device__ __forceinline__ float clip01(float v) { return fminf(fmaxf(v, 0.0f), 1.0f); }

// ---------------------------------------------------------------- pose
__global__ void k_pose(const float* __restrict__ pose_obs,
                       const float* __restrict__ poses_last,
                       const float* __restrict__ eve,
                       float* __restrict__ par,
                       float* __restrict__ out_poses) {
  int b = threadIdx.x;
  if (b >= BS) return;
  const float R2Df = 57.29577951308232f;
  const float D2R  = 0.017453292519943295f;
  float pl0 = poses_last[b*3+0], pl1 = poses_last[b*3+1], pl2 = poses_last[b*3+2];
  float po0 = pose_obs[b*3+0],   po1 = pose_obs[b*3+1],   po2 = pose_obs[b*3+2];
  float r  = pl2 / R2Df;
  float sr = sinf(r), cr = cosf(r);
  float ny = pl1 + po0*sr + po1*cr;
  float nx = pl0 + po0*cr - po1*sr;
  float nt = pl2 + po2*R2Df;
  nt = fmodf(nt - 180.0f, 360.0f) + 180.0f;
  nt = fmodf(nt + 180.0f, 360.0f) - 180.0f;
  out_poses[b*3+0] = nx;
  out_poses[b*3+1] = ny;
  out_poses[b*3+2] = nt;
  float a = eve[b] * D2R;
  par[b*8+0] = cosf(a);
  par[b*8+1] = sinf(a);
  float t = (90.0f - nt) * D2R;
  par[b*8+2] = cosf(t);
  par[b*8+3] = sinf(t);
  par[b*8+4] = (240.0f - nx*100.0f/5.0f) / 240.0f;
  par[b*8+5] = (240.0f - ny*100.0f/5.0f) / 240.0f;
  par[b*8+6] = (eve[b] == 0.0f) ? 1.0f : 0.0f;
  if (b == 0) {
    int sxi = (int)(nx * 100.0f / 5.0f);
    int syi = (int)(ny * 100.0f / 5.0f);
    sxi = min(max(sxi, 30), 449);
    syi = min(max(syi, 30), 449);
    par[32] = (float)sxi;
    par[33] = (float)syi;
    par[34] = (float)(320.0 / tan(39.5 * 0.017453292519943295));  // _F in double, like numpy
  }
}

// ---------------------------------------------------------------- splat (trilinear scatter)
__global__ void k_splat(const float* __restrict__ obs,
                        const float* __restrict__ par,
                        float* __restrict__ vox) {
  int tid = blockIdx.x * blockDim.x + threadIdx.x;
  if (tid >= BS*IMH*IMW) return;
  int j  = tid % IMW;
  int t2 = tid / IMW;
  int i  = t2 % IMH;
  int b  = t2 / IMH;

  float F  = par[34];
  float ca = par[b*8+0], sa = par[b*8+1];
  float depth = obs[(((size_t)b*NCH + 3)*IMH + i)*IMW + j];

  float gx = (float)j;
  float gz = (float)(IMH - 1 - i);
  float X  = (gx - 319.5f) * depth / F;
  float Zc = (gz - 239.5f) * depth / F;
  float Y  = ca*depth - sa*Zc;
  float Z  = sa*depth + ca*Zc + 88.0f;
  X = X + 250.0f;
  float xs = (X/5.0f - 50.0f)/100.0f*2.0f;
  float ys = (Y/5.0f - 50.0f)/100.0f*2.0f;
  float zs = (Z/5.0f - 16.0f)/48.0f*2.0f;
  float px = xs*50.0f + 50.0f;
  float py = ys*50.0f + 50.0f;
  float pz = zs*24.0f + 24.0f;

  float fx = floorf(px), fy = floorf(py), fz = floorf(pz);
  float wxa[2], wya[2], wza[2];
  int   ixa[2], iya[2], iza[2];
#pragma unroll
  for (int k = 0; k < 2; ++k) {
    float pv = fx + (float)k;
    bool s = (pv > 0.0f) && (pv < 100.0f);
    wxa[k] = s ? (1.0f - fabsf(px - pv)) : 0.0f;
    ixa[k] = s ? (int)pv : 0;
    pv = fy + (float)k;
    s = (pv > 0.0f) && (pv < 100.0f);
    wya[k] = s ? (1.0f - fabsf(py - pv)) : 0.0f;
    iya[k] = s ? (int)pv : 0;
    pv = fz + (float)k;
    s = (pv > 0.0f) && (pv < 48.0f);
    wza[k] = s ? (1.0f - fabsf(pz - pv)) : 0.0f;
    iza[k] = s ? (int)pv : 0;
  }
  bool anyX = (wxa[0] != 0.0f) || (wxa[1] != 0.0f);
  bool anyY = (wya[0] != 0.0f) || (wya[1] != 0.0f);
  bool anyZ = (wza[0] != 0.0f) || (wza[1] != 0.0f);
  if (!(anyX && anyY && anyZ)) return;

  bool needSem = false;
#pragma unroll
  for (int k = 0; k < 2; ++k)
    if (wza[k] != 0.0f && iza[k] >= 13 && iza[k] < 35) needSem = true;

  float sem[16];
  if (needSem) {
#pragma unroll
    for (int c = 0; c < 16; ++c)
      sem[c] = obs[(((size_t)b*NCH + 4 + c)*IMH + i)*IMW + j];
  }

#pragma unroll
  for (int cx = 0; cx < 2; ++cx) {
    float wxv = wxa[cx];
    if (wxv == 0.0f) continue;
#pragma unroll
    for (int cy = 0; cy < 2; ++cy) {
      float wxy = wxv * wya[cy];
      if (wxy == 0.0f) continue;
      float* colp = vox + ((size_t)((b*VR + ixa[cx])*VR + iya[cy])) * VOXCOL;
#pragma unroll
      for (int cz = 0; cz < 2; ++cz) {
        float wv = wxy * wza[cz];
        if (wv == 0.0f) continue;
        int zv = iza[cz];
        atomicAdd(colp + zv, wv);                       // feat ch0 == 1
        if (zv >= 13 && zv < 35) {
          float* p2 = colp + 48 + (size_t)(zv - 13)*16;
#pragma unroll
          for (int c = 0; c < 16; ++c) atomicAdd(p2 + c, wv * sem[c]);
        }
      }
    }
  }
}

// ---------------------------------------------------------------- z-reduce (round + clip)
__global__ void k_reduce(const float* __restrict__ vox,
                         float* __restrict__ av,
                         float* __restrict__ avs) {
  int tid = blockIdx.x * blockDim.x + threadIdx.x;
  if (tid >= BS*VR*VR) return;
  int y = tid % VR;
  int x = (tid / VR) % VR;
  int b = tid / (VR*VR);
  const float* col = vox + (size_t)tid * VOXCOL;   // tid == (b*VR+x)*VR+y

  float all0 = 0.0f, ahp0 = 0.0f, asp0 = 0.0f;
#pragma unroll
  for (int z = 0; z < 48; ++z) {
    float v = rintf(col[z]);
    all0 += v;
    if (z >= 13 && z < 35) ahp0 += v;
    if (z >= 20 && z < 25) asp0 += v;
  }
  float acc[16];
#pragma unroll
  for (int c = 0; c < 16; ++c) acc[c] = 0.0f;
  for (int z = 0; z < 22; ++z) {
    const float* p2 = col + 48 + z*16;
#pragma unroll
    for (int c = 0; c < 16; ++c) acc[c] += rintf(p2[c]);
  }
  size_t pxo = (size_t)y*VR + x;
  size_t ab  = (size_t)b*18*10000;
  av[ab + 0*10000 + pxo] = clip01(ahp0);            // fp_map   (MAP_T = 1)
  av[ab + 1*10000 + pxo] = clip01(all0);            // fp_exp   (EXP_T = 1)
#pragma unroll
  for (int c = 0; c < 16; ++c)
    av[ab + (size_t)(2 + c)*10000 + pxo] = clip01(acc[c] / 5.0f);  // CAT_T = 5
  avs[(size_t)b*10000 + pxo] = clip01(asp0);        // fp_stair
}

// ---------------------------------------------------------------- rotation grid_sample
__global__ void k_rot(const float* __restrict__ av,
                      const float* __restrict__ avs,
                      const float* __restrict__ par,
                      float* __restrict__ R) {
  int tid = blockIdx.x * blockDim.x + threadIdx.x;
  if (tid >= BS*MPX) return;
  int w = tid % MSZ;
  int h = (tid / MSZ) % MSZ;
  int b = tid / MPX;

  float ct = par[b*8+2], st = par[b*8+3];
  float gx = ((w + 0.5f)*2.0f)/480.0f - 1.0f;
  float gy = ((h + 0.5f)*2.0f)/480.0f - 1.0f;
  float u = gx*ct - gy*st;
  float v = gx*st + gy*ct;
  float xf = (u + 1.0f)*0.5f*479.0f;
  float yf = (v + 1.0f)*0.5f*479.0f;
  float x0f = floorf(xf), y0f = floorf(yf);
  int x0 = (int)x0f, y0 = (int)y0f;
  // agent_view nonzero only in rows [240,340), cols [190,290): early-out (R pre-zeroed)
  if (x0 < 189 || x0 > 289 || y0 < 239 || y0 > 339) return;
  float wx = xf - x0f, wy = yf - y0f;
  float w00 = (1.0f-wx)*(1.0f-wy), w10 = wx*(1.0f-wy), w01 = (1.0f-wx)*wy, w11 = wx*wy;
  bool vx0 = (x0   >= 190) && (x0   < 290);
  bool vx1 = (x0+1 >= 190) && (x0+1 < 290);
  bool vy0 = (y0   >= 240) && (y0   < 340);
  bool vy1 = (y0+1 >= 240) && (y0+1 < 340);
  int o00 = (y0-240)*100 + (x0-190);
  int o10 = o00 + 1;
  int o01 = o00 + 100;
  int o11 = o00 + 101;
  bool v00 = vx0&&vy0, v10 = vx1&&vy0, v01 = vx0&&vy1, v11 = vx1&&vy1;
  size_t rbase = (size_t)b*19*MPX + (size_t)h*MSZ + w;
#pragma unroll
  for (int s = 0; s < 19; ++s) {
    const float* plane = (s < 18) ? (av + ((size_t)b*18 + s)*10000) : (avs + (size_t)b*10000);
    float g00 = v00 ? plane[o00] : 0.0f;
    float g10 = v10 ? plane[o10] : 0.0f;
    float g01 = v01 ? plane[o01] : 0.0f;
    float g11 = v11 ? plane[o11] : 0.0f;
    R[rbase + (size_t)s*MPX] = g00*w00 + g10*w10 + g01*w01 + g11*w11;
  }
}

// ---------------------------------------------------------------- translation grid_sample
__global__ void k_trans(const float* __restrict__ R,
                        const float* __restrict__ par,
                        float* __restrict__ out0,
                        float* __restrict__ ts0) {
  int tid = blockIdx.x * blockDim.x + threadIdx.x;
  if (tid >= BS*MPX) return;
  int w = tid % MSZ;
  int h = (tid / MSZ) % MSZ;
  int b = tid / MPX;

  float sx = par[b*8+4], sy = par[b*8+5];
  float gx = ((w + 0.5f)*2.0f)/480.0f - 1.0f;
  float gy = ((h + 0.5f)*2.0f)/480.0f - 1.0f;
  float u = gx + sx;
  float v = gy + sy;
  float xf = (u + 1.0f)*0.5f*479.0f;
  float yf = (v + 1.0f)*0.5f*479.0f;
  float x0f = floorf(xf), y0f = floorf(yf);
  int x0 = (int)x0f, y0 = (int)y0f;
  size_t outbase = (size_t)b*NCH*MPX + (size_t)h*MSZ + w;
  size_t tsidx   = (size_t)b*MPX + (size_t)h*MSZ + w;

  if (x0 < -1 || x0 > 479 || y0 < -1 || y0 > 479) {
#pragma unroll
    for (int c = 0; c < NCH; ++c) out0[outbase + (size_t)c*MPX] = 0.0f;
    ts0[tsidx] = 0.0f;
    return;
  }
  float wx = xf - x0f, wy = yf - y0f;
  float w00 = (1.0f-wx)*(1.0f-wy), w10 = wx*(1.0f-wy), w01 = (1.0f-wx)*wy, w11 = wx*wy;
  bool vx0 = (x0   >= 0) && (x0   < 480);
  bool vx1 = (x0+1 >= 0) && (x0+1 < 480);
  bool vy0 = (y0   >= 0) && (y0   < 480);
  bool vy1 = (y0+1 >= 0) && (y0+1 < 480);
  bool v00 = vx0&&vy0, v10 = vx1&&vy0, v01 = vx0&&vy1, v11 = vx1&&vy1;
  int p00 = y0*MSZ + x0;
  size_t rb = (size_t)b*19*MPX;
  float t[19];
#pragma unroll
  for (int s = 0; s < 19; ++s) {
    const float* pl = R + rb + (size_t)s*MPX;
    float g00 = v00 ? pl[p00]       : 0.0f;
    float g10 = v10 ? pl[p00+1]     : 0.0f;
    float g01 = v01 ? pl[p00+MSZ]   : 0.0f;
    float g11 = v11 ? pl[p00+MSZ+1] : 0.0f;
    t[s] = g00*w00 + g10*w10 + g01*w01 + g11*w11;
  }
  out0[outbase + 0*MPX] = t[0];
  out0[outbase + 1*MPX] = t[1];
  out0[outbase + 2*MPX] = 0.0f;
  out0[outbase + 3*MPX] = 0.0f;
#pragma unroll
  for (int c = 0; c < 16; ++c) out0[outbase + (size_t)(4 + c)*MPX] = t[2 + c];
  ts0[tsidx] = t[18];
}

// ---------------------------------------------------------------- final merge
__global__ void k_final(const float* __restrict__ out0,
                        const float* __restrict__ maps_last,
                        const float* __restrict__ ts0buf,
                        const float* __restrict__ par,
                        float* __restrict__ out1,
                        float* __restrict__ out2) {
  int tid = blockIdx.x * blockDim.x + threadIdx.x;
  if (tid >= BS*MPX) return;
  int w = tid % MSZ;
  int h = (tid / MSZ) % MSZ;
  int b = tid / MPX;

  size_t pix = (size_t)h*MSZ + w;
  const float* T  = out0      + (size_t)b*NCH*MPX;
  const float* ML = maps_last + (size_t)b*NCH*MPX;

  // maxpool3 (SAME, -inf pad) of translated ch0
  float mp = -INFINITY;
#pragma unroll
  for (int dh = -1; dh <= 1; ++dh) {
    int hh = h + dh;
    if (hh < 0 || hh >= MSZ) continue;
#pragma unroll
    for (int dw = -1; dw <= 1; ++dw) {
      int ww2 = w + dw;
      if (ww2 < 0 || ww2 >= MSZ) continue;
      mp = fmaxf(mp, T[(size_t)hh*MSZ + ww2]);
    }
  }
  float t1v = T[MPX + pix];
  bool eve0 = (par[b*8+6] != 0.0f);
  bool kill = ((t1v - mp) > 0.8f) && eve0;

  float sg = 1.0f;
  if (b == 0) {
    int sxi = (int)par[32], syi = (int)par[33];
    int di = h - (syi - 30);
    int dj = w - (sxi - 30);
    if (di >= 0 && di < 60 && dj >= 0 && dj < 60) {
      float aa = (float)di - 29.5f;
      float bb = (float)dj - 29.5f;
      sg = (aa*aa + bb*bb <= 900.0f) ? 1.0f : 0.0f;
    } else {
      sg = 0.0f;
    }
  }
  float tsv0 = ts0buf[(size_t)b*MPX + pix] * sg;
  float ts1  = t1v * sg;
  bool kill_s = ((ts1 - tsv0) > 0.8f) && eve0;

#pragma unroll
  for (int c = 0; c < NCH; ++c) {
    size_t idx = (size_t)c*MPX + pix;
    float tv = T[idx];
    float ml = ML[idx];
    float mpv = fmaxf(ml, tv);
    float tsv = (c == 0) ? tsv0 : ((c == 1) ? ts1 : tv);
    float msv = fmaxf(ml, tsv);
    if (c == 0) {
      if (kill)   mpv = 0.0f;
      if (kill_s) msv = 0.0f;
    }
    size_t o = (size_t)b*NCH*MPX + idx;
    out1[o] = mpv;
    out2[o] = msv;
  }
}

// ---------------------------------------------------------------- launch
extern "C" void kernel_launch(void* const* d_in, const int* in_sizes, int n_in,
                              void* d_out, int out_size, void* d_ws, size_t ws_size,
                              hipStream_t stream) {
  (void)in_sizes; (void)n_in; (void)out_size; (void)ws_size;
  const float* obs        = (const float*)d_in[0];
  const float* pose_obs   = (const float*)d_in[1];
  const float* maps_last  = (const float*)d_in[2];
  const float* poses_last = (const float*)d_in[3];
  const float* eve        = (const float*)d_in[4];
  float* out = (float*)d_out;
  float* ws  = (float*)d_ws;

  float* av   = ws + OFF_AV;
  float* avs  = ws + OFF_AVS;
  float* ts0  = ws + OFF_TS0;
  float* par  = ws + OFF_PAR;

  float* out0 = out;
  float* out1 = out + SEG;
  float* out2 = out + 2*SEG;
  float* outp = out + 3*SEG;

  // big scratch lives in the out1/out2 segments (dead before k_final overwrites them)
  float* vox = out1;   // 16,000,000 floats <= SEG
  float* Rb  = out2;   // 17,510,400 floats <= SEG

  k_pose<<<1, 64, 0, stream>>>(pose_obs, poses_last, eve, par, outp);
  hipMemsetAsync(vox, 0, VOX_FLOATS*sizeof(float), stream);
  k_splat<<<(BS*IMH*IMW + 255)/256, 256, 0, stream>>>(obs, par, vox);
  k_reduce<<<(BS*VR*VR + 255)/256, 256, 0, stream>>>(vox, av, avs);
  hipMemsetAsync(Rb, 0, R_FLOATS*sizeof(float), stream);
  k_rot<<<(BS*MPX + 255)/256, 256, 0, stream>>>(av, avs, par, Rb);
  k_trans<<<(BS*MPX + 255)/256, 256, 0, stream>>>(Rb, par, out0, ts0);
  k_final<<<(BS*MPX + 255)/256, 256, 0, stream>>>(out0, maps_last, ts0, par, out1, out2);
}

// Round 2
// 2281.363 us; speedup vs baseline: 1.6943x; 1.6943x over previous
//
#include <hip/hip_runtime.h>
#include <math.h>

#define BS 4
#define NCH 20
#define IMH 480
#define IMW 640
#define MSZ 480
#define MPX (MSZ*MSZ)            /* 230400 */
#define VR 100

// region tiling for the LDS-privatized splat
#define TX 10
#define TY 8
#define NRX 10                   /* 100/10  */
#define NRY 13                   /* ceil(100/8) */
#define CELLS (TX*TY)            /* 80 */
#define CELLF 400                /* 48 ch0-z + 22*16 sem floats per cell */
/* LDS = 80*400*4 = 128000 B */

static constexpr size_t SEG = (size_t)BS*NCH*MPX;              // 18,432,000 floats per map output

// workspace layout (float offsets)
static constexpr size_t OFF_AV  = 0;            // BS*18*100*100 = 720000
static constexpr size_t OFF_AVS = 720000;       // BS*100*100    = 40000
static constexpr size_t OFF_TS0 = 760000;       // BS*MPX        = 921600
static constexpr size_t OFF_PAR = 1681600;      // 64 floats

__device__ __forceinline__ float clip01(float v) { return fminf(fmaxf(v, 0.0f), 1.0f); }

// ---------------------------------------------------------------- pose
__global__ void k_pose(const float* __restrict__ pose_obs,
                       const float* __restrict__ poses_last,
                       const float* __restrict__ eve,
                       float* __restrict__ par,
                       float* __restrict__ out_poses) {
  int b = threadIdx.x;
  if (b >= BS) return;
  const float R2Df = 57.29577951308232f;
  const float D2R  = 0.017453292519943295f;
  float pl0 = poses_last[b*3+0], pl1 = poses_last[b*3+1], pl2 = poses_last[b*3+2];
  float po0 = pose_obs[b*3+0],   po1 = pose_obs[b*3+1],   po2 = pose_obs[b*3+2];
  float r  = pl2 / R2Df;
  float sr = sinf(r), cr = cosf(r);
  float ny = pl1 + po0*sr + po1*cr;
  float nx = pl0 + po0*cr - po1*sr;
  float nt = pl2 + po2*R2Df;
  nt = fmodf(nt - 180.0f, 360.0f) + 180.0f;
  nt = fmodf(nt + 180.0f, 360.0f) - 180.0f;
  out_poses[b*3+0] = nx;
  out_poses[b*3+1] = ny;
  out_poses[b*3+2] = nt;
  float a = eve[b] * D2R;
  par[b*8+0] = cosf(a);
  par[b*8+1] = sinf(a);
  float t = (90.0f - nt) * D2R;
  par[b*8+2] = cosf(t);
  par[b*8+3] = sinf(t);
  par[b*8+4] = (240.0f - nx*100.0f/5.0f) / 240.0f;
  par[b*8+5] = (240.0f - ny*100.0f/5.0f) / 240.0f;
  par[b*8+6] = (eve[b] == 0.0f) ? 1.0f : 0.0f;
  if (b == 0) {
    int sxi = (int)(nx * 100.0f / 5.0f);
    int syi = (int)(ny * 100.0f / 5.0f);
    sxi = min(max(sxi, 30), 449);
    syi = min(max(syi, 30), 449);
    par[32] = (float)sxi;
    par[33] = (float)syi;
    par[34] = (float)(320.0 / tan(39.5 * 0.017453292519943295));  // _F in double, like numpy
  }
}

// ---------------------------------------------------------------- splat + reduce (LDS-privatized per region)
__global__ __launch_bounds__(1024) void k_splat_reduce(const float* __restrict__ obs,
                                                       const float* __restrict__ par,
                                                       float* __restrict__ av,
                                                       float* __restrict__ avs) {
  __shared__ float lds[CELLS * CELLF];
  const int tid = threadIdx.x;
  const int reg = blockIdx.x;          // 0..NRX*NRY-1
  const int b   = blockIdx.y;          // batch
  const int rx0 = (reg % NRX) * TX;
  const int ry0 = (reg / NRX) * TY;

  for (int i = tid; i < CELLS * CELLF; i += 1024) lds[i] = 0.0f;
  __syncthreads();

  const float F    = par[34];
  const float invF = 1.0f / F;
  const float ca = par[b*8+0], sa = par[b*8+1];
  const float* __restrict__ dpl = obs + (((size_t)b*NCH + 3)*IMH)*IMW;
  const float* __restrict__ semb = obs + (((size_t)b*NCH + 4)*IMH)*IMW;

  const float rxlo = (float)rx0, rxhi = (float)(rx0 + TX);
  const float rylo = (float)ry0, ryhi = (float)(ry0 + TY);

  for (int p = tid; p < IMH*IMW; p += 1024) {
    int j = p % IMW;
    int i = p / IMW;
    float depth = dpl[p];
    float dF = depth * invF;

    // X / px  (x projection independent of eve angle)
    float X  = ((float)j - 319.5f) * dF;
    X += 250.0f;
    float xs = (X/5.0f - 50.0f)/100.0f*2.0f;
    float px = xs*50.0f + 50.0f;
    float fx = floorf(px);
    // both x corners outside this region's x-range? skip fast
    if (fx + 1.0f < rxlo || fx > rxhi - 1.0f) continue;

    float gz = (float)(IMH - 1 - i);
    float Zc = (gz - 239.5f) * dF;
    float Y  = ca*depth - sa*Zc;
    float Z  = sa*depth + ca*Zc + 88.0f;
    float ys = (Y/5.0f - 50.0f)/100.0f*2.0f;
    float zs = (Z/5.0f - 16.0f)/48.0f*2.0f;
    float py = ys*50.0f + 50.0f;
    float pz = zs*24.0f + 24.0f;
    float fy = floorf(py), fz = floorf(pz);
    if (fy + 1.0f < rylo || fy > ryhi - 1.0f) continue;

    float wxa[2], wya[2], wza[2];
    int   ixa[2], iya[2], iza[2];
    bool  vx[2], vy[2], vz[2];
#pragma unroll
    for (int k = 0; k < 2; ++k) {
      float pv = fx + (float)k;
      bool sg = (pv > 0.0f) && (pv < 100.0f);
      wxa[k] = sg ? (1.0f - fabsf(px - pv)) : 0.0f;
      ixa[k] = (int)pv;
      vx[k]  = sg && (pv >= rxlo) && (pv < rxhi);

      pv = fy + (float)k;
      sg = (pv > 0.0f) && (pv < 100.0f);
      wya[k] = sg ? (1.0f - fabsf(py - pv)) : 0.0f;
      iya[k] = (int)pv;
      vy[k]  = sg && (pv >= rylo) && (pv < ryhi);

      pv = fz + (float)k;
      sg = (pv > 0.0f) && (pv < 48.0f);
      wza[k] = sg ? (1.0f - fabsf(pz - pv)) : 0.0f;
      iza[k] = (int)pv;
      vz[k]  = sg;
    }
    bool anyXY = (vx[0] || vx[1]) && (vy[0] || vy[1]);
    if (!anyXY) continue;
    bool anyZ = vz[0] || vz[1];
    if (!anyZ) continue;

    bool needSem = false;
#pragma unroll
    for (int k = 0; k < 2; ++k)
      if (vz[k] && iza[k] >= 13 && iza[k] < 35 && wza[k] != 0.0f) needSem = true;

    float sem[16];
    if (needSem) {
#pragma unroll
      for (int c = 0; c < 16; ++c)
        sem[c] = semb[(size_t)c*IMH*IMW + p];
    }

#pragma unroll
    for (int cx = 0; cx < 2; ++cx) {
      if (!vx[cx] || wxa[cx] == 0.0f) continue;
#pragma unroll
      for (int cy = 0; cy < 2; ++cy) {
        if (!vy[cy]) continue;
        float wxy = wxa[cx] * wya[cy];
        if (wxy == 0.0f) continue;
        float* cellp = lds + (size_t)((ixa[cx]-rx0)*TY + (iya[cy]-ry0)) * CELLF;
#pragma unroll
        for (int cz = 0; cz < 2; ++cz) {
          if (!vz[cz]) continue;
          float wv = wxy * wza[cz];
          if (wv == 0.0f) continue;
          int zv = iza[cz];
          atomicAdd(cellp + zv, wv);                 // feat ch0 == 1
          if (zv >= 13 && zv < 35) {
            float* p2 = cellp + 48 + (zv - 13)*16;
#pragma unroll
            for (int c = 0; c < 16; ++c) atomicAdd(p2 + c, wv * sem[c]);
          }
        }
      }
    }
  }
  __syncthreads();

  // fused reduce: round -> sum -> clip -> av/avs
  for (int it = tid; it < CELLS * 17; it += 1024) {
    int cell = it % CELLS;
    int ch   = it / CELLS;      // 0 = ch0 planes, 1..16 = sem
    int lx = cell / TY, ly = cell % TY;
    int x = rx0 + lx, y = ry0 + ly;
    if (y >= 100) continue;
    size_t pxo = (size_t)y*VR + x;
    size_t ab  = (size_t)b*18*10000;
    const float* cellp = lds + (size_t)cell * CELLF;
    if (ch == 0) {
      float all0 = 0.0f, ahp0 = 0.0f, asp0 = 0.0f;
#pragma unroll
      for (int z = 0; z < 48; ++z) {
        float v = rintf(cellp[z]);
        all0 += v;
        if (z >= 13 && z < 35) ahp0 += v;
        if (z >= 20 && z < 25) asp0 += v;
      }
      av[ab + 0*10000 + pxo] = clip01(ahp0);         // fp_map (MAP_T=1)
      av[ab + 1*10000 + pxo] = clip01(all0);         // fp_exp (EXP_T=1)
      avs[(size_t)b*10000 + pxo] = clip01(asp0);     // fp_stair
    } else {
      int c = ch - 1;
      float acc = 0.0f;
      for (int z = 0; z < 22; ++z) acc += rintf(cellp[48 + z*16 + c]);
      av[ab + (size_t)(2 + c)*10000 + pxo] = clip01(acc / 5.0f);  // CAT_T=5
    }
  }
}

// ---------------------------------------------------------------- rotation grid_sample (writes full plane; no memset needed)
__global__ void k_rot(const float* __restrict__ av,
                      const float* __restrict__ avs,
                      const float* __restrict__ par,
                      float* __restrict__ R) {
  int tid = blockIdx.x * blockDim.x + threadIdx.x;
  if (tid >= BS*MPX) return;
  int w = tid % MSZ;
  int h = (tid / MSZ) % MSZ;
  int b = tid / MPX;

  float ct = par[b*8+2], st = par[b*8+3];
  float gx = ((w + 0.5f)*2.0f)/480.0f - 1.0f;
  float gy = ((h + 0.5f)*2.0f)/480.0f - 1.0f;
  float u = gx*ct - gy*st;
  float v = gx*st + gy*ct;
  float xf = (u + 1.0f)*0.5f*479.0f;
  float yf = (v + 1.0f)*0.5f*479.0f;
  float x0f = floorf(xf), y0f = floorf(yf);
  int x0 = (int)x0f, y0 = (int)y0f;
  size_t rbase = (size_t)b*19*MPX + (size_t)h*MSZ + w;
  // agent_view nonzero only in rows [240,340), cols [190,290)
  if (x0 < 189 || x0 > 289 || y0 < 239 || y0 > 339) {
#pragma unroll
    for (int s = 0; s < 19; ++s) R[rbase + (size_t)s*MPX] = 0.0f;
    return;
  }
  float wx = xf - x0f, wy = yf - y0f;
  float w00 = (1.0f-wx)*(1.0f-wy), w10 = wx*(1.0f-wy), w01 = (1.0f-wx)*wy, w11 = wx*wy;
  bool vx0 = (x0   >= 190) && (x0   < 290);
  bool vx1 = (x0+1 >= 190) && (x0+1 < 290);
  bool vy0 = (y0   >= 240) && (y0   < 340);
  bool vy1 = (y0+1 >= 240) && (y0+1 < 340);
  int o00 = (y0-240)*100 + (x0-190);
  int o10 = o00 + 1;
  int o01 = o00 + 100;
  int o11 = o00 + 101;
  bool v00 = vx0&&vy0, v10 = vx1&&vy0, v01 = vx0&&vy1, v11 = vx1&&vy1;
#pragma unroll
  for (int s = 0; s < 19; ++s) {
    const float* plane = (s < 18) ? (av + ((size_t)b*18 + s)*10000) : (avs + (size_t)b*10000);
    float g00 = v00 ? plane[o00] : 0.0f;
    float g10 = v10 ? plane[o10] : 0.0f;
    float g01 = v01 ? plane[o01] : 0.0f;
    float g11 = v11 ? plane[o11] : 0.0f;
    R[rbase + (size_t)s*MPX] = g00*w00 + g10*w10 + g01*w01 + g11*w11;
  }
}

// ---------------------------------------------------------------- translation grid_sample
__global__ void k_trans(const float* __restrict__ R,
                        const float* __restrict__ par,
                        float* __restrict__ out0,
                        float* __restrict__ ts0) {
  int tid = blockIdx.x * blockDim.x + threadIdx.x;
  if (tid >= BS*MPX) return;
  int w = tid % MSZ;
  int h = (tid / MSZ) % MSZ;
  int b = tid / MPX;

  float sx = par[b*8+4], sy = par[b*8+5];
  float gx = ((w + 0.5f)*2.0f)/480.0f - 1.0f;
  float gy = ((h + 0.5f)*2.0f)/480.0f - 1.0f;
  float u = gx + sx;
  float v = gy + sy;
  float xf = (u + 1.0f)*0.5f*479.0f;
  float yf = (v + 1.0f)*0.5f*479.0f;
  float x0f = floorf(xf), y0f = floorf(yf);
  int x0 = (int)x0f, y0 = (int)y0f;
  size_t outbase = (size_t)b*NCH*MPX + (size_t)h*MSZ + w;
  size_t tsidx   = (size_t)b*MPX + (size_t)h*MSZ + w;

  if (x0 < -1 || x0 > 479 || y0 < -1 || y0 > 479) {
#pragma unroll
    for (int c = 0; c < NCH; ++c) out0[outbase + (size_t)c*MPX] = 0.0f;
    ts0[tsidx] = 0.0f;
    return;
  }
  float wx = xf - x0f, wy = yf - y0f;
  float w00 = (1.0f-wx)*(1.0f-wy), w10 = wx*(1.0f-wy), w01 = (1.0f-wx)*wy, w11 = wx*wy;
  bool vx0 = (x0   >= 0) && (x0   < 480);
  bool vx1 = (x0+1 >= 0) && (x0+1 < 480);
  bool vy0 = (y0   >= 0) && (y0   < 480);
  bool vy1 = (y0+1 >= 0) && (y0+1 < 480);
  bool v00 = vx0&&vy0, v10 = vx1&&vy0, v01 = vx0&&vy1, v11 = vx1&&vy1;
  int p00 = y0*MSZ + x0;
  size_t rb = (size_t)b*19*MPX;
  float t[19];
#pragma unroll
  for (int s = 0; s < 19; ++s) {
    const float* pl = R + rb + (size_t)s*MPX;
    float g00 = v00 ? pl[p00]       : 0.0f;
    float g10 = v10 ? pl[p00+1]     : 0.0f;
    float g01 = v01 ? pl[p00+MSZ]   : 0.0f;
    float g11 = v11 ? pl[p00+MSZ+1] : 0.0f;
    t[s] = g00*w00 + g10*w10 + g01*w01 + g11*w11;
  }
  out0[outbase + 0*MPX] = t[0];
  out0[outbase + 1*MPX] = t[1];
  out0[outbase + 2*MPX] = 0.0f;
  out0[outbase + 3*MPX] = 0.0f;
#pragma unroll
  for (int c = 0; c < 16; ++c) out0[outbase + (size_t)(4 + c)*MPX] = t[2 + c];
  ts0[tsidx] = t[18];
}

// ---------------------------------------------------------------- final merge
__global__ void k_final(const float* __restrict__ out0,
                        const float* __restrict__ maps_last,
                        const float* __restrict__ ts0buf,
                        const float* __restrict__ par,
                        float* __restrict__ out1,
                        float* __restrict__ out2) {
  int tid = blockIdx.x * blockDim.x + threadIdx.x;
  if (tid >= BS*MPX) return;
  int w = tid % MSZ;
  int h = (tid / MSZ) % MSZ;
  int b = tid / MPX;

  size_t pix = (size_t)h*MSZ + w;
  const float* T  = out0      + (size_t)b*NCH*MPX;
  const float* ML = maps_last + (size_t)b*NCH*MPX;

  // maxpool3 (SAME, -inf pad) of translated ch0
  float mp = -INFINITY;
#pragma unroll
  for (int dh = -1; dh <= 1; ++dh) {
    int hh = h + dh;
    if (hh < 0 || hh >= MSZ) continue;
#pragma unroll
    for (int dw = -1; dw <= 1; ++dw) {
      int ww2 = w + dw;
      if (ww2 < 0 || ww2 >= MSZ) continue;
      mp = fmaxf(mp, T[(size_t)hh*MSZ + ww2]);
    }
  }
  float t1v = T[MPX + pix];
  bool eve0 = (par[b*8+6] != 0.0f);
  bool kill = ((t1v - mp) > 0.8f) && eve0;

  float sg = 1.0f;
  if (b == 0) {
    int sxi = (int)par[32], syi = (int)par[33];
    int di = h - (syi - 30);
    int dj = w - (sxi - 30);
    if (di >= 0 && di < 60 && dj >= 0 && dj < 60) {
      float aa = (float)di - 29.5f;
      float bb = (float)dj - 29.5f;
      sg = (aa*aa + bb*bb <= 900.0f) ? 1.0f : 0.0f;
    } else {
      sg = 0.0f;
    }
  }
  float tsv0 = ts0buf[(size_t)b*MPX + pix] * sg;
  float ts1  = t1v * sg;
  bool kill_s = ((ts1 - tsv0) > 0.8f) && eve0;

#pragma unroll
  for (int c = 0; c < NCH; ++c) {
    size_t idx = (size_t)c*MPX + pix;
    float tv = T[idx];
    float ml = ML[idx];
    float mpv = fmaxf(ml, tv);
    float tsv = (c == 0) ? tsv0 : ((c == 1) ? ts1 : tv);
    float msv = fmaxf(ml, tsv);
    if (c == 0) {
      if (kill)   mpv = 0.0f;
      if (kill_s) msv = 0.0f;
    }
    size_t o = (size_t)b*NCH*MPX + idx;
    out1[o] = mpv;
    out2[o] = msv;
  }
}

// ---------------------------------------------------------------- launch
extern "C" void kernel_launch(void* const* d_in, const int* in_sizes, int n_in,
                              void* d_out, int out_size, void* d_ws, size_t ws_size,
                              hipStream_t stream) {
  (void)in_sizes; (void)n_in; (void)out_size; (void)ws_size;
  const float* obs        = (const float*)d_in[0];
  const float* pose_obs   = (const float*)d_in[1];
  const float* maps_last  = (const float*)d_in[2];
  const float* poses_last = (const float*)d_in[3];
  const float* eve        = (const float*)d_in[4];
  float* out = (float*)d_out;
  float* ws  = (float*)d_ws;

  float* av   = ws + OFF_AV;
  float* avs  = ws + OFF_AVS;
  float* ts0  = ws + OFF_TS0;
  float* par  = ws + OFF_PAR;

  float* out0 = out;
  float* out1 = out + SEG;
  float* out2 = out + 2*SEG;
  float* outp = out + 3*SEG;

  // big scratch lives in the out2 segment (dead before k_final overwrites it)
  float* Rb = out2;   // BS*19*MPX = 17,510,400 floats <= SEG

  k_pose<<<1, 64, 0, stream>>>(pose_obs, poses_last, eve, par, outp);
  {
    dim3 grid(NRX*NRY, BS);
    k_splat_reduce<<<grid, 1024, 0, stream>>>(obs, par, av, avs);
  }
  k_rot<<<(BS*MPX + 255)/256, 256, 0, stream>>>(av, avs, par, Rb);
  k_trans<<<(BS*MPX + 255)/256, 256, 0, stream>>>(Rb, par, out0, ts0);
  k_final<<<(BS*MPX + 255)/256, 256, 0, stream>>>(out0, maps_last, ts0, par, out1, out2);
}

// Round 3
// 1915.232 us; speedup vs baseline: 2.0182x; 1.1912x over previous
//
#include <hip/hip_runtime.h>
#include <math.h>

#define BS 4
#define NCH 20
#define IMH 480
#define IMW 640
#define NPIX (IMH*IMW)           /* 307200 */
#define MSZ 480
#define MPX (MSZ*MSZ)            /* 230400 */
#define VR 100

// region tiling for the LDS-privatized splat
#define TX 10
#define TY 8
#define NRX 10                   /* 100/10  */
#define NRY 13                   /* ceil(100/8) */
#define NBIN (NRX*NRY)           /* 130 */
#define CELLS (TX*TY)            /* 80 */
#define CELLF 400                /* 48 ch0-z + 22*16 sem floats per cell */
/* LDS = 80*400*4 = 128000 B */

static constexpr size_t SEG = (size_t)BS*NCH*MPX;              // 18,432,000 floats per map output

// workspace layout (float/uint offsets)
static constexpr size_t OFF_AV     = 0;            // BS*18*100*100 = 720000
static constexpr size_t OFF_AVS    = 720000;       // BS*100*100    = 40000
static constexpr size_t OFF_TS0    = 760000;       // BS*MPX        = 921600
static constexpr size_t OFF_PAR    = 1681600;      // 64 floats
static constexpr size_t OFF_COUNTS = 1681664;      // 520 uints
static constexpr size_t OFF_OFFS   = 1682184;      // 520 uints
static constexpr size_t OFF_CURS   = 1682704;      // 520 uints

__device__ __forceinline__ float clip01(float v) { return fminf(fmaxf(v, 0.0f), 1.0f); }

struct Geo { float px, py, pz; };

__device__ __forceinline__ Geo geom(int p, float depth, float F, float ca, float sa) {
  int j = p % IMW;
  int i = p / IMW;
  float dF = depth * (1.0f / F);
  float X  = ((float)j - 319.5f) * dF;
  X += 250.0f;
  float gz = (float)(IMH - 1 - i);
  float Zc = (gz - 239.5f) * dF;
  float Y  = ca*depth - sa*Zc;
  float Z  = sa*depth + ca*Zc + 88.0f;
  float xs = (X/5.0f - 50.0f)/100.0f*2.0f;
  float ys = (Y/5.0f - 50.0f)/100.0f*2.0f;
  float zs = (Z/5.0f - 16.0f)/48.0f*2.0f;
  Geo g;
  g.px = xs*50.0f + 50.0f;
  g.py = ys*50.0f + 50.0f;
  g.pz = zs*24.0f + 24.0f;
  return g;
}

// which region bins (0..129) does this pixel's 8-corner splat touch? (0,1,2 or 4)
__device__ __forceinline__ int pixel_bins(Geo g, int bins[4]) {
  float fx = floorf(g.px), fy = floorf(g.py), fz = floorf(g.pz);
  float fx1 = fx + 1.0f, fy1 = fy + 1.0f, fz1 = fz + 1.0f;
  bool vx0 = (fx  > 0.0f) && (fx  < 100.0f);
  bool vx1 = (fx1 > 0.0f) && (fx1 < 100.0f);
  bool vy0 = (fy  > 0.0f) && (fy  < 100.0f);
  bool vy1 = (fy1 > 0.0f) && (fy1 < 100.0f);
  bool vz0 = (fz  > 0.0f) && (fz  < 48.0f);
  bool vz1 = (fz1 > 0.0f) && (fz1 < 48.0f);
  if (!((vx0||vx1) && (vy0||vy1) && (vz0||vz1))) return 0;
  int rxs[2]; int nx = 0;
  if (vx0) rxs[nx++] = (int)fx / TX;
  if (vx1) { int r = (int)fx1 / TX; if (!nx || r != rxs[0]) rxs[nx++] = r; }
  int rys[2]; int ny = 0;
  if (vy0) rys[ny++] = (int)fy / TY;
  if (vy1) { int r = (int)fy1 / TY; if (!ny || r != rys[0]) rys[ny++] = r; }
  int n = 0;
  for (int a = 0; a < ny; ++a)
    for (int c = 0; c < nx; ++c)
      bins[n++] = rys[a]*NRX + rxs[c];
  return n;
}

// ---------------------------------------------------------------- pose (+ zero bin counts)
__global__ void k_pose(const float* __restrict__ pose_obs,
                       const float* __restrict__ poses_last,
                       const float* __restrict__ eve,
                       float* __restrict__ par,
                       float* __restrict__ out_poses,
                       unsigned* __restrict__ counts) {
  int b = threadIdx.x;
  for (int i = b; i < BS*NBIN; i += 64) counts[i] = 0u;
  if (b >= BS) return;
  const float R2Df = 57.29577951308232f;
  const float D2R  = 0.017453292519943295f;
  float pl0 = poses_last[b*3+0], pl1 = poses_last[b*3+1], pl2 = poses_last[b*3+2];
  float po0 = pose_obs[b*3+0],   po1 = pose_obs[b*3+1],   po2 = pose_obs[b*3+2];
  float r  = pl2 / R2Df;
  float sr = sinf(r), cr = cosf(r);
  float ny = pl1 + po0*sr + po1*cr;
  float nx = pl0 + po0*cr - po1*sr;
  float nt = pl2 + po2*R2Df;
  nt = fmodf(nt - 180.0f, 360.0f) + 180.0f;
  nt = fmodf(nt + 180.0f, 360.0f) - 180.0f;
  out_poses[b*3+0] = nx;
  out_poses[b*3+1] = ny;
  out_poses[b*3+2] = nt;
  float a = eve[b] * D2R;
  par[b*8+0] = cosf(a);
  par[b*8+1] = sinf(a);
  float t = (90.0f - nt) * D2R;
  par[b*8+2] = cosf(t);
  par[b*8+3] = sinf(t);
  par[b*8+4] = (240.0f - nx*100.0f/5.0f) / 240.0f;
  par[b*8+5] = (240.0f - ny*100.0f/5.0f) / 240.0f;
  par[b*8+6] = (eve[b] == 0.0f) ? 1.0f : 0.0f;
  if (b == 0) {
    int sxi = (int)(nx * 100.0f / 5.0f);
    int syi = (int)(ny * 100.0f / 5.0f);
    sxi = min(max(sxi, 30), 449);
    syi = min(max(syi, 30), 449);
    par[32] = (float)sxi;
    par[33] = (float)syi;
    par[34] = (float)(320.0 / tan(39.5 * 0.017453292519943295));  // _F in double, like numpy
  }
}

// ---------------------------------------------------------------- bin count
__global__ __launch_bounds__(256) void k_count(const float* __restrict__ obs,
                                               const float* __restrict__ par,
                                               unsigned* __restrict__ counts) {
  __shared__ unsigned hist[NBIN];
  int tid = threadIdx.x;
  int b   = blockIdx.y;
  for (int i = tid; i < NBIN; i += 256) hist[i] = 0u;
  __syncthreads();
  const float F = par[34], ca = par[b*8+0], sa = par[b*8+1];
  const float* __restrict__ dpl = obs + (((size_t)b*NCH + 3)*IMH)*IMW;
  int base = blockIdx.x * 2048;
#pragma unroll
  for (int k = 0; k < 8; ++k) {
    int p = base + k*256 + tid;
    Geo g = geom(p, dpl[p], F, ca, sa);
    int bins[4];
    int n = pixel_bins(g, bins);
    for (int t = 0; t < n; ++t) atomicAdd(&hist[bins[t]], 1u);
  }
  __syncthreads();
  for (int i = tid; i < NBIN; i += 256) {
    unsigned v = hist[i];
    if (v) atomicAdd(&counts[b*NBIN + i], v);
  }
}

// ---------------------------------------------------------------- exclusive scan of 520 counts
__global__ __launch_bounds__(1024) void k_scan(const unsigned* __restrict__ counts,
                                               unsigned* __restrict__ offs,
                                               unsigned* __restrict__ curs) {
  __shared__ unsigned s[1024];
  int tid = threadIdx.x;
  unsigned c0 = (tid < BS*NBIN) ? counts[tid] : 0u;
  s[tid] = c0;
  __syncthreads();
  for (int off = 1; off < 1024; off <<= 1) {
    unsigned v = (tid >= off) ? s[tid - off] : 0u;
    __syncthreads();
    s[tid] += v;
    __syncthreads();
  }
  if (tid < BS*NBIN) {
    unsigned e = s[tid] - c0;     // exclusive
    offs[tid] = e;
    curs[tid] = e;
  }
}

// ---------------------------------------------------------------- scatter pixel ids into bin lists
__global__ __launch_bounds__(256) void k_scatter(const float* __restrict__ obs,
                                                 const float* __restrict__ par,
                                                 unsigned* __restrict__ curs,
                                                 unsigned* __restrict__ list) {
  __shared__ unsigned hist[NBIN];
  __shared__ unsigned lbase[NBIN];
  __shared__ unsigned slot[NBIN];
  int tid = threadIdx.x;
  int b   = blockIdx.y;
  for (int i = tid; i < NBIN; i += 256) { hist[i] = 0u; slot[i] = 0u; }
  __syncthreads();
  const float F = par[34], ca = par[b*8+0], sa = par[b*8+1];
  const float* __restrict__ dpl = obs + (((size_t)b*NCH + 3)*IMH)*IMW;
  int base = blockIdx.x * 2048;
#pragma unroll
  for (int k = 0; k < 8; ++k) {
    int p = base + k*256 + tid;
    Geo g = geom(p, dpl[p], F, ca, sa);
    int bins[4];
    int n = pixel_bins(g, bins);
    for (int t = 0; t < n; ++t) atomicAdd(&hist[bins[t]], 1u);
  }
  __syncthreads();
  for (int i = tid; i < NBIN; i += 256) {
    unsigned h = hist[i];
    lbase[i] = h ? atomicAdd(&curs[b*NBIN + i], h) : 0u;
  }
  __syncthreads();
#pragma unroll
  for (int k = 0; k < 8; ++k) {
    int p = base + k*256 + tid;
    Geo g = geom(p, dpl[p], F, ca, sa);
    int bins[4];
    int n = pixel_bins(g, bins);
    for (int t = 0; t < n; ++t) {
      int bn = bins[t];
      unsigned sidx = atomicAdd(&slot[bn], 1u);
      list[lbase[bn] + sidx] = (unsigned)p;
    }
  }
}

// ---------------------------------------------------------------- splat + reduce (list-driven, LDS-privatized)
__global__ __launch_bounds__(1024) void k_splat2(const float* __restrict__ obs,
                                                 const float* __restrict__ par,
                                                 const unsigned* __restrict__ offs,
                                                 const unsigned* __restrict__ counts,
                                                 const unsigned* __restrict__ list,
                                                 float* __restrict__ av,
                                                 float* __restrict__ avs) {
  __shared__ float lds[CELLS * CELLF];
  const int tid = threadIdx.x;
  const int reg = blockIdx.x;          // 0..NBIN-1
  const int b   = blockIdx.y;
  const int rx0 = (reg % NRX) * TX;
  const int ry0 = (reg / NRX) * TY;

  for (int i = tid; i < CELLS * CELLF; i += 1024) lds[i] = 0.0f;
  __syncthreads();

  const float F = par[34], ca = par[b*8+0], sa = par[b*8+1];
  const float* __restrict__ dpl  = obs + (((size_t)b*NCH + 3)*IMH)*IMW;
  const float* __restrict__ semb = obs + (((size_t)b*NCH + 4)*IMH)*IMW;

  const unsigned bin   = (unsigned)b*NBIN + reg;
  const unsigned start = offs[bin];
  const unsigned n     = counts[bin];

  for (unsigned ii = tid; ii < n; ii += 1024) {
    int p = (int)list[start + ii];
    Geo g = geom(p, dpl[p], F, ca, sa);
    float px = g.px, py = g.py, pz = g.pz;
    float fx = floorf(px), fy = floorf(py), fz = floorf(pz);

    float wxa[2], wya[2], wza[2];
    int   ixa[2], iya[2], iza[2];
    bool  vx[2], vy[2], vz[2];
#pragma unroll
    for (int k = 0; k < 2; ++k) {
      float pv = fx + (float)k;
      bool sg = (pv > 0.0f) && (pv < 100.0f);
      wxa[k] = sg ? (1.0f - fabsf(px - pv)) : 0.0f;
      ixa[k] = (int)pv;
      vx[k]  = sg && (ixa[k] >= rx0) && (ixa[k] < rx0 + TX);

      pv = fy + (float)k;
      sg = (pv > 0.0f) && (pv < 100.0f);
      wya[k] = sg ? (1.0f - fabsf(py - pv)) : 0.0f;
      iya[k] = (int)pv;
      vy[k]  = sg && (iya[k] >= ry0) && (iya[k] < ry0 + TY);

      pv = fz + (float)k;
      sg = (pv > 0.0f) && (pv < 48.0f);
      wza[k] = sg ? (1.0f - fabsf(pz - pv)) : 0.0f;
      iza[k] = (int)pv;
      vz[k]  = sg;
    }

    bool needSem = false;
#pragma unroll
    for (int k = 0; k < 2; ++k)
      if (vz[k] && iza[k] >= 13 && iza[k] < 35 && wza[k] != 0.0f) needSem = true;

    float sem[16];
    if (needSem) {
#pragma unroll
      for (int c = 0; c < 16; ++c)
        sem[c] = semb[(size_t)c*NPIX + p];
    }

#pragma unroll
    for (int cx = 0; cx < 2; ++cx) {
      if (!vx[cx] || wxa[cx] == 0.0f) continue;
#pragma unroll
      for (int cy = 0; cy < 2; ++cy) {
        if (!vy[cy]) continue;
        float wxy = wxa[cx] * wya[cy];
        if (wxy == 0.0f) continue;
        float* cellp = lds + (size_t)((ixa[cx]-rx0)*TY + (iya[cy]-ry0)) * CELLF;
#pragma unroll
        for (int cz = 0; cz < 2; ++cz) {
          if (!vz[cz]) continue;
          float wv = wxy * wza[cz];
          if (wv == 0.0f) continue;
          int zv = iza[cz];
          atomicAdd(cellp + zv, wv);                 // feat ch0 == 1
          if (zv >= 13 && zv < 35) {
            float* p2 = cellp + 48 + (zv - 13)*16;
#pragma unroll
            for (int c = 0; c < 16; ++c) atomicAdd(p2 + c, wv * sem[c]);
          }
        }
      }
    }
  }
  __syncthreads();

  // fused reduce: round -> sum -> clip -> av/avs
  for (int it = tid; it < CELLS * 17; it += 1024) {
    int cell = it % CELLS;
    int ch   = it / CELLS;      // 0 = ch0 planes, 1..16 = sem
    int lx = cell / TY, ly = cell % TY;
    int x = rx0 + lx, y = ry0 + ly;
    if (y >= 100) continue;
    size_t pxo = (size_t)y*VR + x;
    size_t ab  = (size_t)b*18*10000;
    const float* cellp = lds + (size_t)cell * CELLF;
    if (ch == 0) {
      float all0 = 0.0f, ahp0 = 0.0f, asp0 = 0.0f;
#pragma unroll
      for (int z = 0; z < 48; ++z) {
        float v = rintf(cellp[z]);
        all0 += v;
        if (z >= 13 && z < 35) ahp0 += v;
        if (z >= 20 && z < 25) asp0 += v;
      }
      av[ab + 0*10000 + pxo] = clip01(ahp0);         // fp_map (MAP_T=1)
      av[ab + 1*10000 + pxo] = clip01(all0);         // fp_exp (EXP_T=1)
      avs[(size_t)b*10000 + pxo] = clip01(asp0);     // fp_stair
    } else {
      int c = ch - 1;
      float acc = 0.0f;
      for (int z = 0; z < 22; ++z) acc += rintf(cellp[48 + z*16 + c]);
      av[ab + (size_t)(2 + c)*10000 + pxo] = clip01(acc / 5.0f);  // CAT_T=5
    }
  }
}

// ---------------------------------------------------------------- rotation grid_sample (writes full plane)
__global__ void k_rot(const float* __restrict__ av,
                      const float* __restrict__ avs,
                      const float* __restrict__ par,
                      float* __restrict__ R) {
  int tid = blockIdx.x * blockDim.x + threadIdx.x;
  if (tid >= BS*MPX) return;
  int w = tid % MSZ;
  int h = (tid / MSZ) % MSZ;
  int b = tid / MPX;

  float ct = par[b*8+2], st = par[b*8+3];
  float gx = ((w + 0.5f)*2.0f)/480.0f - 1.0f;
  float gy = ((h + 0.5f)*2.0f)/480.0f - 1.0f;
  float u = gx*ct - gy*st;
  float v = gx*st + gy*ct;
  float xf = (u + 1.0f)*0.5f*479.0f;
  float yf = (v + 1.0f)*0.5f*479.0f;
  float x0f = floorf(xf), y0f = floorf(yf);
  int x0 = (int)x0f, y0 = (int)y0f;
  size_t rbase = (size_t)b*19*MPX + (size_t)h*MSZ + w;
  // agent_view nonzero only in rows [240,340), cols [190,290)
  if (x0 < 189 || x0 > 289 || y0 < 239 || y0 > 339) {
#pragma unroll
    for (int s = 0; s < 19; ++s) R[rbase + (size_t)s*MPX] = 0.0f;
    return;
  }
  float wx = xf - x0f, wy = yf - y0f;
  float w00 = (1.0f-wx)*(1.0f-wy), w10 = wx*(1.0f-wy), w01 = (1.0f-wx)*wy, w11 = wx*wy;
  bool vx0 = (x0   >= 190) && (x0   < 290);
  bool vx1 = (x0+1 >= 190) && (x0+1 < 290);
  bool vy0 = (y0   >= 240) && (y0   < 340);
  bool vy1 = (y0+1 >= 240) && (y0+1 < 340);
  int o00 = (y0-240)*100 + (x0-190);
  int o10 = o00 + 1;
  int o01 = o00 + 100;
  int o11 = o00 + 101;
  bool v00 = vx0&&vy0, v10 = vx1&&vy0, v01 = vx0&&vy1, v11 = vx1&&vy1;
#pragma unroll
  for (int s = 0; s < 19; ++s) {
    const float* plane = (s < 18) ? (av + ((size_t)b*18 + s)*10000) : (avs + (size_t)b*10000);
    float g00 = v00 ? plane[o00] : 0.0f;
    float g10 = v10 ? plane[o10] : 0.0f;
    float g01 = v01 ? plane[o01] : 0.0f;
    float g11 = v11 ? plane[o11] : 0.0f;
    R[rbase + (size_t)s*MPX] = g00*w00 + g10*w10 + g01*w01 + g11*w11;
  }
}

// ---------------------------------------------------------------- translation grid_sample
__global__ void k_trans(const float* __restrict__ R,
                        const float* __restrict__ par,
                        float* __restrict__ out0,
                        float* __restrict__ ts0) {
  int tid = blockIdx.x * blockDim.x + threadIdx.x;
  if (tid >= BS*MPX) return;
  int w = tid % MSZ;
  int h = (tid / MSZ) % MSZ;
  int b = tid / MPX;

  float sx = par[b*8+4], sy = par[b*8+5];
  float gx = ((w + 0.5f)*2.0f)/480.0f - 1.0f;
  float gy = ((h + 0.5f)*2.0f)/480.0f - 1.0f;
  float u = gx + sx;
  float v = gy + sy;
  float xf = (u + 1.0f)*0.5f*479.0f;
  float yf = (v + 1.0f)*0.5f*479.0f;
  float x0f = floorf(xf), y0f = floorf(yf);
  int x0 = (int)x0f, y0 = (int)y0f;
  size_t outbase = (size_t)b*NCH*MPX + (size_t)h*MSZ + w;
  size_t tsidx   = (size_t)b*MPX + (size_t)h*MSZ + w;

  if (x0 < -1 || x0 > 479 || y0 < -1 || y0 > 479) {
#pragma unroll
    for (int c = 0; c < NCH; ++c) out0[outbase + (size_t)c*MPX] = 0.0f;
    ts0[tsidx] = 0.0f;
    return;
  }
  float wx = xf - x0f, wy = yf - y0f;
  float w00 = (1.0f-wx)*(1.0f-wy), w10 = wx*(1.0f-wy), w01 = (1.0f-wx)*wy, w11 = wx*wy;
  bool vx0 = (x0   >= 0) && (x0   < 480);
  bool vx1 = (x0+1 >= 0) && (x0+1 < 480);
  bool vy0 = (y0   >= 0) && (y0   < 480);
  bool vy1 = (y0+1 >= 0) && (y0+1 < 480);
  bool v00 = vx0&&vy0, v10 = vx1&&vy0, v01 = vx0&&vy1, v11 = vx1&&vy1;
  int p00 = y0*MSZ + x0;
  size_t rb = (size_t)b*19*MPX;
  float t[19];
#pragma unroll
  for (int s = 0; s < 19; ++s) {
    const float* pl = R + rb + (size_t)s*MPX;
    float g00 = v00 ? pl[p00]       : 0.0f;
    float g10 = v10 ? pl[p00+1]     : 0.0f;
    float g01 = v01 ? pl[p00+MSZ]   : 0.0f;
    float g11 = v11 ? pl[p00+MSZ+1] : 0.0f;
    t[s] = g00*w00 + g10*w10 + g01*w01 + g11*w11;
  }
  out0[outbase + 0*MPX] = t[0];
  out0[outbase + 1*MPX] = t[1];
  out0[outbase + 2*MPX] = 0.0f;
  out0[outbase + 3*MPX] = 0.0f;
#pragma unroll
  for (int c = 0; c < 16; ++c) out0[outbase + (size_t)(4 + c)*MPX] = t[2 + c];
  ts0[tsidx] = t[18];
}

// ---------------------------------------------------------------- final merge
__global__ void k_final(const float* __restrict__ out0,
                        const float* __restrict__ maps_last,
                        const float* __restrict__ ts0buf,
                        const float* __restrict__ par,
                        float* __restrict__ out1,
                        float* __restrict__ out2) {
  int tid = blockIdx.x * blockDim.x + threadIdx.x;
  if (tid >= BS*MPX) return;
  int w = tid % MSZ;
  int h = (tid / MSZ) % MSZ;
  int b = tid / MPX;

  size_t pix = (size_t)h*MSZ + w;
  const float* T  = out0      + (size_t)b*NCH*MPX;
  const float* ML = maps_last + (size_t)b*NCH*MPX;

  // maxpool3 (SAME, -inf pad) of translated ch0
  float mp = -INFINITY;
#pragma unroll
  for (int dh = -1; dh <= 1; ++dh) {
    int hh = h + dh;
    if (hh < 0 || hh >= MSZ) continue;
#pragma unroll
    for (int dw = -1; dw <= 1; ++dw) {
      int ww2 = w + dw;
      if (ww2 < 0 || ww2 >= MSZ) continue;
      mp = fmaxf(mp, T[(size_t)hh*MSZ + ww2]);
    }
  }
  float t1v = T[MPX + pix];
  bool eve0 = (par[b*8+6] != 0.0f);
  bool kill = ((t1v - mp) > 0.8f) && eve0;

  float sg = 1.0f;
  if (b == 0) {
    int sxi = (int)par[32], syi = (int)par[33];
    int di = h - (syi - 30);
    int dj = w - (sxi - 30);
    if (di >= 0 && di < 60 && dj >= 0 && dj < 60) {
      float aa = (float)di - 29.5f;
      float bb = (float)dj - 29.5f;
      sg = (aa*aa + bb*bb <= 900.0f) ? 1.0f : 0.0f;
    } else {
      sg = 0.0f;
    }
  }
  float tsv0 = ts0buf[(size_t)b*MPX + pix] * sg;
  float ts1  = t1v * sg;
  bool kill_s = ((ts1 - tsv0) > 0.8f) && eve0;

#pragma unroll
  for (int c = 0; c < NCH; ++c) {
    size_t idx = (size_t)c*MPX + pix;
    float tv = T[idx];
    float ml = ML[idx];
    float mpv = fmaxf(ml, tv);
    float tsv = (c == 0) ? tsv0 : ((c == 1) ? ts1 : tv);
    float msv = fmaxf(ml, tsv);
    if (c == 0) {
      if (kill)   mpv = 0.0f;
      if (kill_s) msv = 0.0f;
    }
    size_t o = (size_t)b*NCH*MPX + idx;
    out1[o] = mpv;
    out2[o] = msv;
  }
}

// ---------------------------------------------------------------- launch
extern "C" void kernel_launch(void* const* d_in, const int* in_sizes, int n_in,
                              void* d_out, int out_size, void* d_ws, size_t ws_size,
                              hipStream_t stream) {
  (void)in_sizes; (void)n_in; (void)out_size; (void)ws_size;
  const float* obs        = (const float*)d_in[0];
  const float* pose_obs   = (const float*)d_in[1];
  const float* maps_last  = (const float*)d_in[2];
  const float* poses_last = (const float*)d_in[3];
  const float* eve        = (const float*)d_in[4];
  float* out = (float*)d_out;
  float* ws  = (float*)d_ws;

  float*    av     = ws + OFF_AV;
  float*    avs    = ws + OFF_AVS;
  float*    ts0    = ws + OFF_TS0;
  float*    par    = ws + OFF_PAR;
  unsigned* counts = (unsigned*)(ws + OFF_COUNTS);
  unsigned* offs   = (unsigned*)(ws + OFF_OFFS);
  unsigned* curs   = (unsigned*)(ws + OFF_CURS);

  float* out0 = out;
  float* out1 = out + SEG;
  float* out2 = out + 2*SEG;
  float* outp = out + 3*SEG;

  // big scratch lives in dead output segments:
  unsigned* list = (unsigned*)out1;  // pixel-id bin lists (<= 4.9M entries, cap 18.4M) — dead before k_final
  float*    Rb   = out2;             // rotated planes, BS*19*MPX floats — dead before k_final

  k_pose<<<1, 64, 0, stream>>>(pose_obs, poses_last, eve, par, outp, counts);
  {
    dim3 g(NPIX/2048, BS);
    k_count<<<g, 256, 0, stream>>>(obs, par, counts);
    k_scan<<<1, 1024, 0, stream>>>(counts, offs, curs);
    k_scatter<<<g, 256, 0, stream>>>(obs, par, curs, list);
  }
  {
    dim3 g(NBIN, BS);
    k_splat2<<<g, 1024, 0, stream>>>(obs, par, offs, counts, list, av, avs);
  }
  k_rot<<<(BS*MPX + 255)/256, 256, 0, stream>>>(av, avs, par, Rb);
  k_trans<<<(BS*MPX + 255)/256, 256, 0, stream>>>(Rb, par, out0, ts0);
  k_final<<<(BS*MPX + 255)/256, 256, 0, stream>>>(out0, maps_last, ts0, par, out1, out2);
}

// Round 4
// 302.556 us; speedup vs baseline: 12.7757x; 6.3302x over previous
//
#include <hip/hip_runtime.h>
#include <math.h>

#define BS 4
#define NCH 20
#define IMH 480
#define IMW 640
#define NPIX (IMH*IMW)           /* 307200 */
#define MSZ 480
#define MPX (MSZ*MSZ)            /* 230400 */
#define VR 100

#define TX 5
#define TY 8
#define NRX 20
#define NRY 13
#define NBIN (NRX*NRY)           /* 260 */
#define CELLS (TX*TY)            /* 40 */
#define CELLF 401                /* odd stride -> LDS bank spread; 64160 B -> 2 blocks/CU */

#define FPSCALE 65536.0f
#define FPINV   (1.0f/65536.0f)

static constexpr size_t SEG = (size_t)BS*NCH*MPX;
static constexpr size_t SEMT_FLOATS = (size_t)BS*NPIX*16;
static constexpr size_t LIST_OFF    = SEMT_FLOATS;
static_assert(SEMT_FLOATS < 2*SEG, "semT must fit in out0+out1 segments");

static constexpr size_t OFF_AV     = 0;
static constexpr size_t OFF_AVS    = 720000;
static constexpr size_t OFF_TS0    = 760000;
static constexpr size_t OFF_PAR    = 1681600;
static constexpr size_t OFF_COUNTS = 1681664;
static constexpr size_t OFF_OFFS   = 1682704;
static constexpr size_t OFF_CURS   = 1683744;

__device__ __forceinline__ float clip01(float v) { return fminf(fmaxf(v, 0.0f), 1.0f); }

struct Geo { float px, py, pz; };

__device__ __forceinline__ Geo geom(int p, float depth, float F, float ca, float sa) {
  int j = p % IMW;
  int i = p / IMW;
  float dF = depth * (1.0f / F);
  float X  = ((float)j - 319.5f) * dF;
  X += 250.0f;
  float gz = (float)(IMH - 1 - i);
  float Zc = (gz - 239.5f) * dF;
  float Y  = ca*depth - sa*Zc;
  float Z  = sa*depth + ca*Zc + 88.0f;
  float xs = (X/5.0f - 50.0f)/100.0f*2.0f;
  float ys = (Y/5.0f - 50.0f)/100.0f*2.0f;
  float zs = (Z/5.0f - 16.0f)/48.0f*2.0f;
  Geo g;
  g.px = xs*50.0f + 50.0f;
  g.py = ys*50.0f + 50.0f;
  g.pz = zs*24.0f + 24.0f;
  return g;
}

__device__ __forceinline__ int pixel_bins(Geo g, int bins[4]) {
  float fx = floorf(g.px), fy = floorf(g.py), fz = floorf(g.pz);
  float fx1 = fx + 1.0f, fy1 = fy + 1.0f, fz1 = fz + 1.0f;
  bool vx0 = (fx  > 0.0f) && (fx  < 100.0f);
  bool vx1 = (fx1 > 0.0f) && (fx1 < 100.0f);
  bool vy0 = (fy  > 0.0f) && (fy  < 100.0f);
  bool vy1 = (fy1 > 0.0f) && (fy1 < 100.0f);
  bool vz0 = (fz  > 0.0f) && (fz  < 48.0f);
  bool vz1 = (fz1 > 0.0f) && (fz1 < 48.0f);
  if (!((vx0||vx1) && (vy0||vy1) && (vz0||vz1))) return 0;
  int rxs[2]; int nx = 0;
  if (vx0) rxs[nx++] = (int)fx / TX;
  if (vx1) { int r = (int)fx1 / TX; if (!nx || r != rxs[0]) rxs[nx++] = r; }
  int rys[2]; int ny = 0;
  if (vy0) rys[ny++] = (int)fy / TY;
  if (vy1) { int r = (int)fy1 / TY; if (!ny || r != rys[0]) rys[ny++] = r; }
  int n = 0;
  for (int a = 0; a < ny; ++a)
    for (int c = 0; c < nx; ++c)
      bins[n++] = rys[a]*NRX + rxs[c];
  return n;
}

__global__ void k_pose(const float* __restrict__ pose_obs,
                       const float* __restrict__ poses_last,
                       const float* __restrict__ eve,
                       float* __restrict__ par,
                       float* __restrict__ out_poses,
                       unsigned* __restrict__ counts) {
  int b = threadIdx.x;
  for (int i = b; i < BS*NBIN; i += 64) counts[i] = 0u;
  if (b >= BS) return;
  const float R2Df = 57.29577951308232f;
  const float D2R  = 0.017453292519943295f;
  float pl0 = poses_last[b*3+0], pl1 = poses_last[b*3+1], pl2 = poses_last[b*3+2];
  float po0 = pose_obs[b*3+0],   po1 = pose_obs[b*3+1],   po2 = pose_obs[b*3+2];
  float r  = pl2 / R2Df;
  float sr = sinf(r), cr = cosf(r);
  float ny = pl1 + po0*sr + po1*cr;
  float nx = pl0 + po0*cr - po1*sr;
  float nt = pl2 + po2*R2Df;
  nt = fmodf(nt - 180.0f, 360.0f) + 180.0f;
  nt = fmodf(nt + 180.0f, 360.0f) - 180.0f;
  out_poses[b*3+0] = nx;
  out_poses[b*3+1] = ny;
  out_poses[b*3+2] = nt;
  float a = eve[b] * D2R;
  par[b*8+0] = cosf(a);
  par[b*8+1] = sinf(a);
  float t = (90.0f - nt) * D2R;
  par[b*8+2] = cosf(t);
  par[b*8+3] = sinf(t);
  par[b*8+4] = (240.0f - nx*100.0f/5.0f) / 240.0f;
  par[b*8+5] = (240.0f - ny*100.0f/5.0f) / 240.0f;
  par[b*8+6] = (eve[b] == 0.0f) ? 1.0f : 0.0f;
  if (b == 0) {
    int sxi = (int)(nx * 100.0f / 5.0f);
    int syi = (int)(ny * 100.0f / 5.0f);
    sxi = min(max(sxi, 30), 449);
    syi = min(max(syi, 30), 449);
    par[32] = (float)sxi;
    par[33] = (float)syi;
    par[34] = (float)(320.0 / tan(39.5 * 0.017453292519943295));
  }
}

__global__ __launch_bounds__(256) void k_transpose(const float* __restrict__ obs,
                                                   float* __restrict__ semT) {
  int p = blockIdx.x * 256 + threadIdx.x;
  int b = blockIdx.y;
  const float* __restrict__ semb = obs + ((size_t)b*NCH + 4)*NPIX;
  float s[16];
#pragma unroll
  for (int c = 0; c < 16; ++c) s[c] = semb[(size_t)c*NPIX + p];
  float4* dst = (float4*)(semT + ((size_t)b*NPIX + p)*16);
  dst[0] = make_float4(s[0],  s[1],  s[2],  s[3]);
  dst[1] = make_float4(s[4],  s[5],  s[6],  s[7]);
  dst[2] = make_float4(s[8],  s[9],  s[10], s[11]);
  dst[3] = make_float4(s[12], s[13], s[14], s[15]);
}

__global__ __launch_bounds__(256) void k_count(const float* __restrict__ obs,
                                               const float* __restrict__ par,
                                               unsigned* __restrict__ counts) {
  __shared__ unsigned hist[NBIN];
  int tid = threadIdx.x;
  int b   = blockIdx.y;
  for (int i = tid; i < NBIN; i += 256) hist[i] = 0u;
  __syncthreads();
  const float F = par[34], ca = par[b*8+0], sa = par[b*8+1];
  const float* __restrict__ dpl = obs + (((size_t)b*NCH + 3)*IMH)*IMW;
  int base = blockIdx.x * 2048;
#pragma unroll
  for (int k = 0; k < 8; ++k) {
    int p = base + k*256 + tid;
    Geo g = geom(p, dpl[p], F, ca, sa);
    int bins[4];
    int n = pixel_bins(g, bins);
    for (int t = 0; t < n; ++t) atomicAdd(&hist[bins[t]], 1u);
  }
  __syncthreads();
  for (int i = tid; i < NBIN; i += 256) {
    unsigned v = hist[i];
    if (v) atomicAdd(&counts[b*NBIN + i], v);
  }
}

__global__ __launch_bounds__(1024) void k_scan(const unsigned* __restrict__ counts,
                                               unsigned* __restrict__ offs,
                                               unsigned* __restrict__ curs) {
  __shared__ unsigned s[1024];
  int t = threadIdx.x;
  const int n2 = BS*NBIN;   // 1040 <= 2048
  unsigned a  = (2*t   < n2) ? counts[2*t]   : 0u;
  unsigned bb = (2*t+1 < n2) ? counts[2*t+1] : 0u;
  unsigned pr = a + bb;
  s[t] = pr;
  __syncthreads();
  for (int off = 1; off < 1024; off <<= 1) {
    unsigned v = (t >= off) ? s[t - off] : 0u;
    __syncthreads();
    s[t] += v;
    __syncthreads();
  }
  unsigned excl = s[t] - pr;
  if (2*t < n2)   { offs[2*t]   = excl;     curs[2*t]   = excl;     }
  if (2*t+1 < n2) { offs[2*t+1] = excl + a; curs[2*t+1] = excl + a; }
}

__global__ __launch_bounds__(256) void k_scatter(const float* __restrict__ obs,
                                                 const float* __restrict__ par,
                                                 unsigned* __restrict__ curs,
                                                 unsigned* __restrict__ list) {
  __shared__ unsigned hist[NBIN];
  __shared__ unsigned lbase[NBIN];
  __shared__ unsigned slot[NBIN];
  int tid = threadIdx.x;
  int b   = blockIdx.y;
  for (int i = tid; i < NBIN; i += 256) { hist[i] = 0u; slot[i] = 0u; }
  __syncthreads();
  const float F = par[34], ca = par[b*8+0], sa = par[b*8+1];
  const float* __restrict__ dpl = obs + (((size_t)b*NCH + 3)*IMH)*IMW;
  int base = blockIdx.x * 2048;
#pragma unroll
  for (int k = 0; k < 8; ++k) {
    int p = base + k*256 + tid;
    Geo g = geom(p, dpl[p], F, ca, sa);
    int bins[4];
    int n = pixel_bins(g, bins);
    for (int t = 0; t < n; ++t) atomicAdd(&hist[bins[t]], 1u);
  }
  __syncthreads();
  for (int i = tid; i < NBIN; i += 256) {
    unsigned h = hist[i];
    lbase[i] = h ? atomicAdd(&curs[b*NBIN + i], h) : 0u;
  }
  __syncthreads();
#pragma unroll
  for (int k = 0; k < 8; ++k) {
    int p = base + k*256 + tid;
    Geo g = geom(p, dpl[p], F, ca, sa);
    int bins[4];
    int n = pixel_bins(g, bins);
    for (int t = 0; t < n; ++t) {
      int bn = bins[t];
      unsigned sidx = atomicAdd(&slot[bn], 1u);
      list[lbase[bn] + sidx] = (unsigned)p;
    }
  }
}

__global__ __launch_bounds__(1024) void k_splat2(const float* __restrict__ obs,
                                                 const float* __restrict__ semT,
                                                 const float* __restrict__ par,
                                                 const unsigned* __restrict__ offs,
                                                 const unsigned* __restrict__ counts,
                                                 const unsigned* __restrict__ list,
                                                 float* __restrict__ av,
                                                 float* __restrict__ avs) {
  __shared__ unsigned lds[CELLS * CELLF];
  const int tid = threadIdx.x;
  const int reg = blockIdx.x;
  const int b   = blockIdx.y;
  const int rx0 = (reg % NRX) * TX;
  const int ry0 = (reg / NRX) * TY;

  for (int i = tid; i < CELLS * CELLF; i += 1024) lds[i] = 0u;
  __syncthreads();

  const float F = par[34], ca = par[b*8+0], sa = par[b*8+1];
  const float* __restrict__ dpl = obs + (((size_t)b*NCH + 3)*IMH)*IMW;

  const unsigned bin   = (unsigned)b*NBIN + reg;
  const unsigned start = offs[bin];
  const unsigned n     = counts[bin];

  for (unsigned ii = tid; ii < n; ii += 1024) {
    int p = (int)list[start + ii];
    Geo g = geom(p, dpl[p], F, ca, sa);
    float px = g.px, py = g.py, pz = g.pz;
    float fx = floorf(px), fy = floorf(py), fz = floorf(pz);

    float wxa[2], wya[2], wza[2];
    int   ixa[2], iya[2], iza[2];
    bool  vx[2], vy[2], vz[2];
#pragma unroll
    for (int k = 0; k < 2; ++k) {
      float pv = fx + (float)k;
      bool sg = (pv > 0.0f) && (pv < 100.0f);
      wxa[k] = sg ? (1.0f - fabsf(px - pv)) : 0.0f;
      ixa[k] = (int)pv;
      vx[k]  = sg && (ixa[k] >= rx0) && (ixa[k] < rx0 + TX);

      pv = fy + (float)k;
      sg = (pv > 0.0f) && (pv < 100.0f);
      wya[k] = sg ? (1.0f - fabsf(py - pv)) : 0.0f;
      iya[k] = (int)pv;
      vy[k]  = sg && (iya[k] >= ry0) && (iya[k] < ry0 + TY);

      pv = fz + (float)k;
      sg = (pv > 0.0f) && (pv < 48.0f);
      wza[k] = sg ? (1.0f - fabsf(pz - pv)) : 0.0f;
      iza[k] = (int)pv;
      vz[k]  = sg;
    }

    bool needSem = false;
#pragma unroll
    for (int k = 0; k < 2; ++k)
      if (vz[k] && iza[k] >= 13 && iza[k] < 35 && wza[k] != 0.0f) needSem = true;

    float sem[16];
    if (needSem) {
      const float4* sp = (const float4*)(semT + ((size_t)b*NPIX + p)*16);
      float4 s0 = sp[0], s1 = sp[1], s2 = sp[2], s3 = sp[3];
      sem[0]=s0.x; sem[1]=s0.y; sem[2]=s0.z; sem[3]=s0.w;
      sem[4]=s1.x; sem[5]=s1.y; sem[6]=s1.z; sem[7]=s1.w;
      sem[8]=s2.x; sem[9]=s2.y; sem[10]=s2.z; sem[11]=s2.w;
      sem[12]=s3.x; sem[13]=s3.y; sem[14]=s3.z; sem[15]=s3.w;
    }

#pragma unroll
    for (int cx = 0; cx < 2; ++cx) {
      if (!vx[cx] || wxa[cx] == 0.0f) continue;
#pragma unroll
      for (int cy = 0; cy < 2; ++cy) {
        if (!vy[cy]) continue;
        float wxy = wxa[cx] * wya[cy];
        if (wxy == 0.0f) continue;
        unsigned* cellp = lds + (size_t)((ixa[cx]-rx0)*TY + (iya[cy]-ry0)) * CELLF;
#pragma unroll
        for (int cz = 0; cz < 2; ++cz) {
          if (!vz[cz]) continue;
          float wv = wxy * wza[cz];
          if (wv == 0.0f) continue;
          int zv = iza[cz];
          atomicAdd(cellp + zv, (unsigned)(wv*FPSCALE + 0.5f));
          if (zv >= 13 && zv < 35) {
            unsigned* p2 = cellp + 48 + (zv - 13)*16;
#pragma unroll
            for (int c = 0; c < 16; ++c)
              atomicAdd(p2 + c, (unsigned)(wv*sem[c]*FPSCALE + 0.5f));
          }
        }
      }
    }
  }
  __syncthreads();

  for (int it = tid; it < CELLS * 17; it += 1024) {
    int cell = it % CELLS;
    int ch   = it / CELLS;
    int lx = cell / TY, ly = cell % TY;
    int x = rx0 + lx, y = ry0 + ly;
    if (y >= 100) continue;
    size_t pxo = (size_t)y*VR + x;
    size_t ab  = (size_t)b*18*10000;
    const unsigned* cellp = lds + (size_t)cell * CELLF;
    if (ch == 0) {
      float all0 = 0.0f, ahp0 = 0.0f, asp0 = 0.0f;
#pragma unroll
      for (int z = 0; z < 48; ++z) {
        float v = rintf((float)cellp[z] * FPINV);
        all0 += v;
        if (z >= 13 && z < 35) ahp0 += v;
        if (z >= 20 && z < 25) asp0 += v;
      }
      av[ab + 0*10000 + pxo] = clip01(ahp0);
      av[ab + 1*10000 + pxo] = clip01(all0);
      avs[(size_t)b*10000 + pxo] = clip01(asp0);
    } else {
      int c = ch - 1;
      float acc = 0.0f;
      for (int z = 0; z < 22; ++z) acc += rintf((float)cellp[48 + z*16 + c] * FPINV);
      av[ab + (size_t)(2 + c)*10000 + pxo] = clip01(acc / 5.0f);
    }
  }
}

__global__ void k_rot(const float* __restrict__ av,
                      const float* __restrict__ avs,
                      const float* __restrict__ par,
                      float* __restrict__ R) {
  int tid = blockIdx.x * blockDim.x + threadIdx.x;
  if (tid >= BS*MPX) return;
  int w = tid % MSZ;
  int h = (tid / MSZ) % MSZ;
  int b = tid / MPX;

  float ct = par[b*8+2], st = par[b*8+3];
  float gx = ((w + 0.5f)*2.0f)/480.0f - 1.0f;
  float gy = ((h + 0.5f)*2.0f)/480.0f - 1.0f;
  float u = gx*ct - gy*st;
  float v = gx*st + gy*ct;
  float xf = (u + 1.0f)*0.5f*479.0f;
  float yf = (v + 1.0f)*0.5f*479.0f;
  float x0f = floorf(xf), y0f = floorf(yf);
  int x0 = (int)x0f, y0 = (int)y0f;
  size_t rbase = (size_t)b*19*MPX + (size_t)h*MSZ + w;
  if (x0 < 189 || x0 > 289 || y0 < 239 || y0 > 339) {
#pragma unroll
    for (int s = 0; s < 19; ++s) R[rbase + (size_t)s*MPX] = 0.0f;
    return;
  }
  float wx = xf - x0f, wy = yf - y0f;
  float w00 = (1.0f-wx)*(1.0f-wy), w10 = wx*(1.0f-wy), w01 = (1.0f-wx)*wy, w11 = wx*wy;
  bool vx0 = (x0   >= 190) && (x0   < 290);
  bool vx1 = (x0+1 >= 190) && (x0+1 < 290);
  bool vy0 = (y0   >= 240) && (y0   < 340);
  bool vy1 = (y0+1 >= 240) && (y0+1 < 340);
  int o00 = (y0-240)*100 + (x0-190);
  int o10 = o00 + 1;
  int o01 = o00 + 100;
  int o11 = o00 + 101;
  bool v00 = vx0&&vy0, v10 = vx1&&vy0, v01 = vx0&&vy1, v11 = vx1&&vy1;
#pragma unroll
  for (int s = 0; s < 19; ++s) {
    const float* plane = (s < 18) ? (av + ((size_t)b*18 + s)*10000) : (avs + (size_t)b*10000);
    float g00 = v00 ? plane[o00] : 0.0f;
    float g10 = v10 ? plane[o10] : 0.0f;
    float g01 = v01 ? plane[o01] : 0.0f;
    float g11 = v11 ? plane[o11] : 0.0f;
    R[rbase + (size_t)s*MPX] = g00*w00 + g10*w10 + g01*w01 + g11*w11;
  }
}

__global__ void k_trans(const float* __restrict__ R,
                        const float* __restrict__ par,
                        float* __restrict__ out0,
                        float* __restrict__ ts0) {
  int tid = blockIdx.x * blockDim.x + threadIdx.x;
  if (tid >= BS*MPX) return;
  int w = tid % MSZ;
  int h = (tid / MSZ) % MSZ;
  int b = tid / MPX;

  float sx = par[b*8+4], sy = par[b*8+5];
  float gx = ((w + 0.5f)*2.0f)/480.0f - 1.0f;
  float gy = ((h + 0.5f)*2.0f)/480.0f - 1.0f;
  float u = gx + sx;
  float v = gy + sy;
  float xf = (u + 1.0f)*0.5f*479.0f;
  float yf = (v + 1.0f)*0.5f*479.0f;
  float x0f = floorf(xf), y0f = floorf(yf);
  int x0 = (int)x0f, y0 = (int)y0f;
  size_t outbase = (size_t)b*NCH*MPX + (size_t)h*MSZ + w;
  size_t tsidx   = (size_t)b*MPX + (size_t)h*MSZ + w;

  if (x0 < -1 || x0 > 479 || y0 < -1 || y0 > 479) {
#pragma unroll
    for (int c = 0; c < NCH; ++c) out0[outbase + (size_t)c*MPX] = 0.0f;
    ts0[tsidx] = 0.0f;
    return;
  }
  float wx = xf - x0f, wy = yf - y0f;
  float w00 = (1.0f-wx)*(1.0f-wy), w10 = wx*(1.0f-wy), w01 = (1.0f-wx)*wy, w11 = wx*wy;
  bool vx0 = (x0   >= 0) && (x0   < 480);
  bool vx1 = (x0+1 >= 0) && (x0+1 < 480);
  bool vy0 = (y0   >= 0) && (y0   < 480);
  bool vy1 = (y0+1 >= 0) && (y0+1 < 480);
  bool v00 = vx0&&vy0, v10 = vx1&&vy0, v01 = vx0&&vy1, v11 = vx1&&vy1;
  int p00 = y0*MSZ + x0;
  size_t rb = (size_t)b*19*MPX;
  float t[19];
#pragma unroll
  for (int s = 0; s < 19; ++s) {
    const float* pl = R + rb + (size_t)s*MPX;
    float g00 = v00 ? pl[p00]       : 0.0f;
    float g10 = v10 ? pl[p00+1]     : 0.0f;
    float g01 = v01 ? pl[p00+MSZ]   : 0.0f;
    float g11 = v11 ? pl[p00+MSZ+1] : 0.0f;
    t[s] = g00*w00 + g10*w10 + g01*w01 + g11*w11;
  }
  out0[outbase + 0*MPX] = t[0];
  out0[outbase + 1*MPX] = t[1];
  out0[outbase + 2*MPX] = 0.0f;
  out0[outbase + 3*MPX] = 0.0f;
#pragma unroll
  for (int c = 0; c < 16; ++c) out0[outbase + (size_t)(4 + c)*MPX] = t[2 + c];
  ts0[tsidx] = t[18];
}

__global__ void k_final(const float* __restrict__ out0,
                        const float* __restrict__ maps_last,
                        const float* __restrict__ ts0buf,
                        const float* __restrict__ par,
                        float* __restrict__ out1,
                        float* __restrict__ out2) {
  int tid = blockIdx.x * blockDim.x + threadIdx.x;
  if (tid >= BS*MPX) return;
  int w = tid % MSZ;
  int h = (tid / MSZ) % MSZ;
  int b = tid / MPX;

  size_t pix = (size_t)h*MSZ + w;
  const float* T  = out0      + (size_t)b*NCH*MPX;
  const float* ML = maps_last + (size_t)b*NCH*MPX;

  float mp = -INFINITY;
#pragma unroll
  for (int dh = -1; dh <= 1; ++dh) {
    int hh = h + dh;
    if (hh < 0 || hh >= MSZ) continue;
#pragma unroll
    for (int dw = -1; dw <= 1; ++dw) {
      int ww2 = w + dw;
      if (ww2 < 0 || ww2 >= MSZ) continue;
      mp = fmaxf(mp, T[(size_t)hh*MSZ + ww2]);
    }
  }
  float t1v = T[MPX + pix];
  bool eve0 = (par[b*8+6] != 0.0f);
  bool kill = ((t1v - mp) > 0.8f) && eve0;

  float sg = 1.0f;
  if (b == 0) {
    int sxi = (int)par[32], syi = (int)par[33];
    int di = h - (syi - 30);
    int dj = w - (sxi - 30);
    if (di >= 0 && di < 60 && dj >= 0 && dj < 60) {
      float aa = (float)di - 29.5f;
      float bb = (float)dj - 29.5f;
      sg = (aa*aa + bb*bb <= 900.0f) ? 1.0f : 0.0f;
    } else {
      sg = 0.0f;
    }
  }
  float tsv0 = ts0buf[(size_t)b*MPX + pix] * sg;
  float ts1  = t1v * sg;
  bool kill_s = ((ts1 - tsv0) > 0.8f) && eve0;

#pragma unroll
  for (int c = 0; c < NCH; ++c) {
    size_t idx = (size_t)c*MPX + pix;
    float tv = T[idx];
    float ml = ML[idx];
    float mpv = fmaxf(ml, tv);
    float tsv = (c == 0) ? tsv0 : ((c == 1) ? ts1 : tv);
    float msv = fmaxf(ml, tsv);
    if (c == 0) {
      if (kill)   mpv = 0.0f;
      if (kill_s) msv = 0.0f;
    }
    size_t o = (size_t)b*NCH*MPX + idx;
    out1[o] = mpv;
    out2[o] = msv;
  }
}

extern "C" void kernel_launch(void* const* d_in, const int* in_sizes, int n_in,
                              void* d_out, int out_size, void* d_ws, size_t ws_size,
                              hipStream_t stream) {
  (void)in_sizes; (void)n_in; (void)out_size; (void)ws_size;
  const float* obs        = (const float*)d_in[0];
  const float* pose_obs   = (const float*)d_in[1];
  const float* maps_last  = (const float*)d_in[2];
  const float* poses_last = (const float*)d_in[3];
  const float* eve        = (const float*)d_in[4];
  float* out = (float*)d_out;
  float* ws  = (float*)d_ws;

  float*    av     = ws + OFF_AV;
  float*    avs    = ws + OFF_AVS;
  float*    ts0    = ws + OFF_TS0;
  float*    par    = ws + OFF_PAR;
  unsigned* counts = (unsigned*)(ws + OFF_COUNTS);
  unsigned* offs   = (unsigned*)(ws + OFF_OFFS);
  unsigned* curs   = (unsigned*)(ws + OFF_CURS);

  float* out0 = out;
  float* out1 = out + SEG;
  float* out2 = out + 2*SEG;
  float* outp = out + 3*SEG;

  float*    semT = out0;                        // spans out0 + head of out1; dead before k_trans
  unsigned* list = (unsigned*)(out + LIST_OFF); // dead before k_final
  float*    Rb   = out2;                        // dead before k_final

  k_pose<<<1, 64, 0, stream>>>(pose_obs, poses_last, eve, par, outp, counts);
  {
    dim3 gt(NPIX/256, BS);
    k_transpose<<<gt, 256, 0, stream>>>(obs, semT);
    dim3 g(NPIX/2048, BS);
    k_count<<<g, 256, 0, stream>>>(obs, par, counts);
    k_scan<<<1, 1024, 0, stream>>>(counts, offs, curs);
    k_scatter<<<g, 256, 0, stream>>>(obs, par, curs, list);
  }
  {
    dim3 g(NBIN, BS);
    k_splat2<<<g, 1024, 0, stream>>>(obs, semT, par, offs, counts, list, av, avs);
  }
  k_rot<<<(BS*MPX + 255)/256, 256, 0, stream>>>(av, avs, par, Rb);
  k_trans<<<(BS*MPX + 255)/256, 256, 0, stream>>>(Rb, par, out0, ts0);
  k_final<<<(BS*MPX + 255)/256, 256, 0, stream>>>(out0, maps_last, ts0, par, out1, out2);
}